// Round 10
// baseline (425.139 us; speedup 1.0000x reference)
//
#include <hip/hip_runtime.h>
#include <hip/hip_bf16.h>

// Problem: B=128, T=256, D=1024.  TOK = B*T = 32768.
// keys = x@Wk.T+bk ; queries = x@Wq.T+bq ; values = x@Wv.T+bv
// S = tril(Q K^T / 32) ; P = softmax(S) ; out = P V   (fp32 out)

typedef __attribute__((ext_vector_type(4))) float f32x4;
typedef __attribute__((ext_vector_type(8))) short s16x8;
typedef unsigned short u16;

__device__ inline u16 f2bf(float f) {
    union { __hip_bfloat16 h; u16 u; } c;
    c.h = __float2bfloat16(f);
    return c.u;
}

// async global->LDS DMA, 16B/lane, dest = wave-uniform base + lane*16
__device__ __forceinline__ void stage16(const void* g, void* l) {
    __builtin_amdgcn_global_load_lds((const __attribute__((address_space(1))) void*)g,
                                     (__attribute__((address_space(3))) void*)l, 16, 0, 0);
}

#define MFMA(a_, b_, c_) (c_) = __builtin_amdgcn_mfma_f32_16x16x32_bf16((a_), (b_), (c_), 0, 0, 0)

// ---------------- fp32 -> bf16 convert ----------------
__global__ __launch_bounds__(256) void cvt_f32_bf16(const float* __restrict__ in,
                                                    u16* __restrict__ out, int n4) {
    int stride = gridDim.x * blockDim.x;
    for (int i = blockIdx.x * blockDim.x + threadIdx.x; i < n4; i += stride) {
        float4 v = reinterpret_cast<const float4*>(in)[i];
        ushort4 o = make_ushort4(f2bf(v.x), f2bf(v.y), f2bf(v.z), f2bf(v.w));
        reinterpret_cast<ushort4*>(out)[i] = o;
    }
}

// ====== 128x256-tile QKV GEMM @ 2 BLOCKS/CU (the untested lever) ======
// Hypothesis: all prior variants ran 1 block/CU (128 KiB LDS) -> all 8 waves
// phase-locked by block barriers -> MFMA pipe idle outside the MFMA phase
// (27% = 2048 cyc MFMA-work / 7500 cyc K-tile, measured invariant over 7
// schedules).  m97/m103 (912 TF) hid the same stalls via ~3 resident blocks,
// draining vmcnt(0) every step.  This kernel: BM=128 BN=256 BK=32, LDS
// 2x24 KiB = 48 KiB, __launch_bounds__(512,4) caps VGPR at 128 -> 2 blocks/CU.
// Per step u: STAGE(u+1)->buf[(u+1)&1]; 8 ds_read (tile u); 16 MFMA; vmcnt(0);
// barrier.  WAR: buf[(u+1)&1] last read at step u-1 (reads drained before that
// step's MFMAs + barrier).  RAW: tile u staged at u-1, drained by that step's
// vmcnt(0)+barrier.  The drain stall is hidden by the co-resident block.
// Bank swizzle (exact 2-way = free): phys slot = logical ^ ((row>>1)&3);
// (row&1, (row>>1)&3) covers all 8 bank-quads exactly twice per 16-lane read.
// DMA dest linear; global SOURCE pre-swizzled with the same involution.
// Lane-uniformity: row = {wr,wc}*64 + f*16 + l15 -> (row>>1)&3 = (l15>>1)&3.
__global__ __launch_bounds__(512, 4) void qkv128(const u16* __restrict__ X, const u16* __restrict__ W3,
                                                 const float* __restrict__ biasK,
                                                 const float* __restrict__ biasQ,
                                                 const float* __restrict__ biasV,
                                                 u16* __restrict__ Kb, u16* __restrict__ Qb,
                                                 u16* __restrict__ Vt) {
    __shared__ char lds[49152];   // 2 bufs x 24576: A [128][32] @+0 (8K), B [256][32] @+8192 (16K)

    const int bid = blockIdx.x;
    const int swz = (bid & 7) * 384 + (bid >> 3);   // 3072 % 8 == 0: bijective XCD swizzle
    const int mt = swz / 12, nt2 = swz % 12;        // 256 m-tiles x (3 mats x 4 col-tiles)
    const int nmat = nt2 >> 2, ncol = nt2 & 3;
    const u16* Asrc = X + (size_t)mt * 128 * 1024;
    const u16* Bsrc = W3 + (size_t)nmat * 1048576 + (size_t)ncol * 256 * 1024;

    const int tid  = threadIdx.x;
    const int lane = tid & 63, w = tid >> 6;
    const int wr = w >> 2, wc = w & 3;              // 2M x 4N waves, per-wave 64x64
    const int l15 = lane & 15, l16 = lane >> 4;

    // swizzled ds_read offset: row l15 within a 16-row frag, k-slot l16
    const int rdoff = l15 * 64 + (((l16 ^ ((l15 >> 1) & 3)) & 3) << 4);
    const int aoff = wr * 4096 + rdoff;             // + fm*1024
    const int boff = 8192 + wc * 4096 + rdoff;      // + fn*1024

    // staging: thread t -> row t>>2, linear slot t&3; src col pre-swizzled
    const int srow = tid >> 2, sslot = tid & 3;
    const int scol = (sslot ^ ((srow >> 1) & 3)) * 8;       // elements
    const u16* asrcp  = Asrc + (size_t)srow * 1024 + scol;
    const u16* bsrcp0 = Bsrc + (size_t)srow * 1024 + scol;          // B rows 0-127
    const u16* bsrcp1 = Bsrc + (size_t)(srow + 128) * 1024 + scol;  // B rows 128-255 (same swz: +128 == 0 mod 8)

    f32x4 acc[4][4] = {};

    // one K-tile (BK=32) = 24 KB = 3 DMA rounds (8 KB each)
#define STG(u_) do {                                                              \
        char* bb_ = lds + (((u_) & 1) * 24576) + w * 1024;                        \
        const size_t ko_ = (size_t)(u_) * 32;                                     \
        stage16(asrcp  + ko_, bb_);                                               \
        stage16(bsrcp0 + ko_, bb_ + 8192);                                        \
        stage16(bsrcp1 + ko_, bb_ + 16384);                                       \
    } while (0)

    STG(0);
    asm volatile("s_waitcnt vmcnt(0)" ::: "memory");
    __builtin_amdgcn_s_barrier();

    for (int u = 0; u < 32; ++u) {
        if (u < 31) STG(u + 1);
        const char* bp = lds + (u & 1) * 24576;
        s16x8 a[4], b[4];
#pragma unroll
        for (int fm = 0; fm < 4; ++fm) a[fm] = *(const s16x8*)(bp + aoff + fm * 1024);
#pragma unroll
        for (int fn = 0; fn < 4; ++fn) b[fn] = *(const s16x8*)(bp + boff + fn * 1024);
        __builtin_amdgcn_s_setprio(1);
#pragma unroll
        for (int fm = 0; fm < 4; ++fm)
#pragma unroll
            for (int fn = 0; fn < 4; ++fn)
                MFMA(a[fm], b[fn], acc[fm][fn]);
        __builtin_amdgcn_s_setprio(0);
        asm volatile("s_waitcnt vmcnt(0)" ::: "memory");
        __builtin_amdgcn_s_barrier();
    }
#undef STG

    // ---- epilogue: bias + convert + store ----
    const float* bias = (nmat == 0) ? biasK : (nmat == 1) ? biasQ : biasV;
    u16* outKQ = (nmat == 0) ? Kb : Qb;
    const int r0 = l16 << 2;
#pragma unroll
    for (int m = 0; m < 4; ++m) {
#pragma unroll
        for (int n = 0; n < 4; ++n) {
            const int col = ncol * 256 + wc * 64 + n * 16 + l15;
            const float bvv = bias[col];
            const int rbase = mt * 128 + wr * 64 + m * 16 + r0;
#pragma unroll
            for (int j = 0; j < 4; ++j) {
                const int row = rbase + j;
                const u16 hb = f2bf(acc[m][n][j] + bvv);
                if (nmat == 2) {
                    const int b2 = row >> 8, tt2 = row & 255;
                    Vt[(size_t)b2 * 262144 + (size_t)col * 256 + tt2] = hb;
                } else {
                    outKQ[(size_t)row * 1024 + col] = hb;
                }
            }
        }
    }
}

// ---------------- R1 reg-staged 128x128 mainloop (scores / pv) ----------------
__device__ inline void gemm_mainloop(const u16* __restrict__ Ap, const u16* __restrict__ Bp,
                                     int lda, int ldb, int kLen,
                                     u16* As, u16* Bs, f32x4 (&acc)[4][4]) {
    const int tid  = threadIdx.x;
    const int lane = tid & 63;
    const int wr   = (tid >> 7) & 1;
    const int wc   = (tid >> 6) & 1;
    const int sr   = tid >> 3;
    const int sc   = (tid & 7) << 3;

    for (int k0 = 0; k0 < kLen; k0 += 64) {
#pragma unroll
        for (int it = 0; it < 4; ++it) {
            int r = it * 32 + sr;
            *reinterpret_cast<s16x8*>(&As[r * 64 + sc]) =
                *reinterpret_cast<const s16x8*>(&Ap[(size_t)r * lda + k0 + sc]);
            *reinterpret_cast<s16x8*>(&Bs[r * 64 + sc]) =
                *reinterpret_cast<const s16x8*>(&Bp[(size_t)r * ldb + k0 + sc]);
        }
        __syncthreads();
#pragma unroll
        for (int kk = 0; kk < 64; kk += 32) {
            const int kcol = kk + (lane >> 4) * 8;
            s16x8 a[4], bfr[4];
#pragma unroll
            for (int m = 0; m < 4; ++m)
                a[m] = *reinterpret_cast<const s16x8*>(&As[(wr * 64 + m * 16 + (lane & 15)) * 64 + kcol]);
#pragma unroll
            for (int n = 0; n < 4; ++n)
                bfr[n] = *reinterpret_cast<const s16x8*>(&Bs[(wc * 64 + n * 16 + (lane & 15)) * 64 + kcol]);
#pragma unroll
            for (int m = 0; m < 4; ++m)
#pragma unroll
                for (int n = 0; n < 4; ++n)
                    acc[m][n] = __builtin_amdgcn_mfma_f32_16x16x32_bf16(a[m], bfr[n], acc[m][n], 0, 0, 0);
        }
        __syncthreads();
    }
}

// ---------------- scores: S = tril(Q K^T * 1/32) per batch ----------------
__global__ __launch_bounds__(256) void scores_gemm(const u16* __restrict__ Qb,
                                                   const u16* __restrict__ Kb,
                                                   float* __restrict__ S) {
    __shared__ u16 As[128 * 64];
    __shared__ u16 Bs[128 * 64];
    const int bid = blockIdx.x;
    const int b   = bid / 3;
    const int rem = bid % 3;
    const int ti  = (rem == 0) ? 0 : 1;
    const int si  = (rem == 2) ? 1 : 0;
    const u16* Ap = Qb + ((size_t)b * 256 + (size_t)ti * 128) * 1024;
    const u16* Bp = Kb + ((size_t)b * 256 + (size_t)si * 128) * 1024;

    f32x4 acc[4][4] = {};
    gemm_mainloop(Ap, Bp, 1024, 1024, 1024, As, Bs, acc);

    const int tid  = threadIdx.x;
    const int lane = tid & 63;
    const int wr   = (tid >> 7) & 1;
    const int wc   = (tid >> 6) & 1;
    const int r0 = (lane >> 4) << 2;
    const int c0 = lane & 15;
    const float scale = 0.03125f;
#pragma unroll
    for (int m = 0; m < 4; ++m) {
#pragma unroll
        for (int n = 0; n < 4; ++n) {
            const int s = si * 128 + wc * 64 + n * 16 + c0;
#pragma unroll
            for (int j = 0; j < 4; ++j) {
                const int t = ti * 128 + wr * 64 + m * 16 + r0 + j;
                float v = acc[m][n][j] * scale;
                if (s > t) v = -__builtin_inff();
                S[(size_t)b * 65536 + (size_t)t * 256 + s] = v;
            }
        }
    }
}

// ---------------- row softmax -> P (bf16), zeros above diagonal ----------------
__global__ __launch_bounds__(256) void softmax_p(const float* __restrict__ S, u16* __restrict__ P) {
    const int row  = blockIdx.x * 4 + (threadIdx.x >> 6);
    const int lane = threadIdx.x & 63;
    const int b = row >> 8, t = row & 255;
    const float* Sp = S + (size_t)b * 65536 + (size_t)t * 256;
    const int s0 = lane * 4;
    float4 v = reinterpret_cast<const float4*>(Sp)[lane];
    const float NEG = -__builtin_inff();
    float x0 = (s0 + 0 <= t) ? v.x : NEG;
    float x1 = (s0 + 1 <= t) ? v.y : NEG;
    float x2 = (s0 + 2 <= t) ? v.z : NEG;
    float x3 = (s0 + 3 <= t) ? v.w : NEG;
    float mx = fmaxf(fmaxf(x0, x1), fmaxf(x2, x3));
#pragma unroll
    for (int off = 1; off < 64; off <<= 1) mx = fmaxf(mx, __shfl_xor(mx, off, 64));
    float e0 = (s0 + 0 <= t) ? __expf(x0 - mx) : 0.f;
    float e1 = (s0 + 1 <= t) ? __expf(x1 - mx) : 0.f;
    float e2 = (s0 + 2 <= t) ? __expf(x2 - mx) : 0.f;
    float e3 = (s0 + 3 <= t) ? __expf(x3 - mx) : 0.f;
    float sum = e0 + e1 + e2 + e3;
#pragma unroll
    for (int off = 1; off < 64; off <<= 1) sum += __shfl_xor(sum, off, 64);
    const float inv = 1.0f / sum;
    ushort4 o = make_ushort4(f2bf(e0 * inv), f2bf(e1 * inv), f2bf(e2 * inv), f2bf(e3 * inv));
    reinterpret_cast<ushort4*>(P + (size_t)row * 256)[lane] = o;
}

// ---------------- PV: out = P @ V  (Vt is [b][d][t] so NT) ----------------
__global__ __launch_bounds__(256) void pv_gemm(const u16* __restrict__ P, const u16* __restrict__ Vt,
                                               float* __restrict__ O) {
    __shared__ u16 As[128 * 64];
    __shared__ u16 Bs[128 * 64];
    const int bid = blockIdx.x;
    const int b   = bid >> 4;
    const int r   = bid & 15;
    const int mt  = r >> 3;
    const int ntl = r & 7;
    const u16* Ap = P + (size_t)b * 65536 + (size_t)mt * 128 * 256;
    const u16* Bp = Vt + (size_t)b * 262144 + (size_t)ntl * 128 * 256;
    const int kmax = (mt + 1) * 128;

    f32x4 acc[4][4] = {};
    gemm_mainloop(Ap, Bp, 256, 256, kmax, As, Bs, acc);

    const int tid  = threadIdx.x;
    const int lane = tid & 63;
    const int wr   = (tid >> 7) & 1;
    const int wc   = (tid >> 6) & 1;
    const int r0 = (lane >> 4) << 2;
    const int c0 = lane & 15;
#pragma unroll
    for (int m = 0; m < 4; ++m) {
#pragma unroll
        for (int n = 0; n < 4; ++n) {
            const int d = ntl * 128 + wc * 64 + n * 16 + c0;
#pragma unroll
            for (int j = 0; j < 4; ++j) {
                const int t = mt * 128 + wr * 64 + m * 16 + r0 + j;
                O[((size_t)b * 256 + t) * 1024 + d] = acc[m][n][j];
            }
        }
    }
}

// ---------------- launcher ----------------
extern "C" void kernel_launch(void* const* d_in, const int* in_sizes, int n_in,
                              void* d_out, int out_size, void* d_ws, size_t ws_size,
                              hipStream_t stream) {
    (void)in_sizes; (void)n_in; (void)out_size; (void)ws_size;
    const float* x  = (const float*)d_in[0];
    const float* Wk = (const float*)d_in[1];
    const float* bk = (const float*)d_in[2];
    const float* Wq = (const float*)d_in[3];
    const float* bq = (const float*)d_in[4];
    const float* Wv = (const float*)d_in[5];
    const float* bv = (const float*)d_in[6];
    float* out = (float*)d_out;
    char* ws = (char*)d_ws;

    u16*   xb = (u16*)(ws + 0);
    u16*   Wb = (u16*)(ws + 67108864);
    u16*   Kb = (u16*)(ws + 73400320);
    u16*   Qb = (u16*)(ws + 140509184);
    u16*   Vt = (u16*)(ws + 207618048);
    float* S  = (float*)(ws + 0);
    u16*   P  = (u16*)(ws + 33554432);

    cvt_f32_bf16<<<2048, 256, 0, stream>>>(x, xb, 33554432 / 4);
    cvt_f32_bf16<<<512, 256, 0, stream>>>(Wk, Wb, 1048576 / 4);
    cvt_f32_bf16<<<512, 256, 0, stream>>>(Wq, Wb + 1048576, 1048576 / 4);
    cvt_f32_bf16<<<512, 256, 0, stream>>>(Wv, Wb + 2097152, 1048576 / 4);
    qkv128<<<3072, 512, 0, stream>>>(xb, Wb, bk, bq, bv, Kb, Qb, Vt);
    scores_gemm<<<384, 256, 0, stream>>>(Qb, Kb, S);
    softmax_p<<<8192, 256, 0, stream>>>(S, P);
    pv_gemm<<<2048, 256, 0, stream>>>(P, Vt, out);
}